// Round 1
// baseline (5201.848 us; speedup 1.0000x reference)
//
#include <hip/hip_runtime.h>
#include <math.h>

#define C 64
#define NL 30
#define T 16384
#define B 4

constexpr float INV_SQRT2 = 0.70710678118654752440f;
constexpr float INV_SQRT_NL = 0.18257418583505537115f; // 1/sqrt(30)

// ---------------------------------------------------------------------------
// Transpose weights to oc-contiguous layouts so per-layer weight reads are
// wave-uniform (scalar s_load) in the layer kernel.
//   dwT[l][k][ic][oc]  <- dw_W[l][oc][ic][k]   (oc in [0,128), ic in [0,64), k in [0,3))
//   opT[l][ic][oc]     <- op_W[l][oc][ic]      (kernel size 1)
// ---------------------------------------------------------------------------
__global__ void transpose_weights(const float* __restrict__ dw_W,
                                  const float* __restrict__ op_W,
                                  float* __restrict__ dwT,
                                  float* __restrict__ opT) {
    int idx = blockIdx.x * 256 + threadIdx.x;
    const int ndw = NL * 2 * C * C * 3;   // 737280
    const int nop = NL * 2 * C * C;       // 245760
    if (idx < ndw) {
        int k = idx % 3; int r = idx / 3;
        int ic = r % C; r /= C;
        int oc = r % (2 * C); int l = r / (2 * C);
        dwT[((l * 3 + k) * C + ic) * (2 * C) + oc] = dw_W[idx];
    } else if (idx < ndw + nop) {
        int j = idx - ndw;
        int ic = j % C; int r = j / C;
        int oc = r % (2 * C); int l = r / (2 * C);
        opT[(l * C + ic) * (2 * C) + oc] = op_W[j];
    }
}

// ---------------------------------------------------------------------------
// Diffusion-step embedding -> p1 -> p2 -> per-layer cond projections.
// One block per batch element. cond layout: [NL][B][C].
// ---------------------------------------------------------------------------
__global__ void cond_kernel(const int* __restrict__ step,
                            const float* __restrict__ p1_W, const float* __restrict__ p1_b,
                            const float* __restrict__ p2_W, const float* __restrict__ p2_b,
                            const float* __restrict__ dp_W, const float* __restrict__ dp_b,
                            float* __restrict__ cond) {
    __shared__ float e[128];
    __shared__ float h1[512];
    __shared__ float h2[512];
    int b = blockIdx.x;
    int tid = threadIdx.x;
    int s = step[b];
    if (tid < 128) {
        int d = tid & 63;
        float tf = (float)s * powf(10.f, (float)d * 4.f / 63.f);
        double td = (double)tf;
        e[tid] = (tid < 64) ? (float)sin(td) : (float)cos(td);
    }
    __syncthreads();
    for (int o = tid; o < 512; o += 256) {
        float a = p1_b[o];
        const float* wrow = p1_W + o * 128;
        for (int j = 0; j < 128; ++j) a = fmaf(e[j], wrow[j], a);
        h1[o] = a / (1.f + expf(-a));
    }
    __syncthreads();
    for (int o = tid; o < 512; o += 256) {
        float a = p2_b[o];
        const float* wrow = p2_W + o * 512;
        for (int j = 0; j < 512; ++j) a = fmaf(h1[j], wrow[j], a);
        h2[o] = a / (1.f + expf(-a));
    }
    __syncthreads();
    for (int o = tid; o < NL * C; o += 256) {
        int l = o / C, c2 = o % C;
        float a = dp_b[o];
        const float* wrow = dp_W + o * 512;
        for (int j = 0; j < 512; ++j) a = fmaf(h2[j], wrow[j], a);
        cond[(l * B + b) * C + c2] = a;
    }
}

// ---------------------------------------------------------------------------
// Input 1x1 conv + ReLU: x[b][c][t] = relu(in_W[c]*audio[b][t] + in_b[c])
// ---------------------------------------------------------------------------
__global__ void in_conv(const float* __restrict__ audio,
                        const float* __restrict__ in_W, const float* __restrict__ in_b,
                        float* __restrict__ x) {
    int idx = blockIdx.x * 256 + threadIdx.x;
    int t = idx % T; int r = idx / T; int c = r % C; int b = r / C;
    float v = fmaf(in_W[c], audio[b * T + t], in_b[c]);
    x[idx] = fmaxf(v, 0.f);
}

// ---------------------------------------------------------------------------
// One residual layer, fully fused:
//   y = dilated_conv3(x + cond)          (C -> 2C)
//   z = sigmoid(y[:C]) * tanh(y[C:])
//   o = conv1x1(z)                       (C -> 2C)
//   x_out = (x + o[:C]) / sqrt(2) ; skip (+)= o[C:]
// Block: 128 threads = 2 waves. Wave w handles output channels [w*64, w*64+64).
// Lane l handles t = blockIdx.x*64 + l. Weights read via uniform (SGPR) loads.
// ---------------------------------------------------------------------------
__global__ __launch_bounds__(128) void layer_kernel(
    const float* __restrict__ x_in, float* __restrict__ x_out, float* __restrict__ skip,
    const float* __restrict__ dwT, const float* __restrict__ opT,
    const float* __restrict__ dw_b, const float* __restrict__ op_b,
    const float* __restrict__ cond, int layer, int dil, int first)
{
    __shared__ float zs[C][72];
    __shared__ float cond_s[C];
    int b = blockIdx.y;
    int t0 = blockIdx.x * 64;
    int tid = threadIdx.x;
    int w = __builtin_amdgcn_readfirstlane(tid >> 6);   // wave id, forced uniform
    int l = tid & 63;
    int t = t0 + l;
    if (tid < C) cond_s[tid] = cond[(layer * B + b) * C + tid];
    __syncthreads();

    const float* xb = x_in + (size_t)b * C * T;
    int ocb = w * 64;

    float acc[64];
    const float* dwb_l = dw_b + layer * 2 * C;
    #pragma unroll
    for (int oc = 0; oc < 64; ++oc) acc[oc] = dwb_l[ocb + oc];

    const float* Wl = dwT + (size_t)layer * 3 * C * 2 * C;
    for (int k = 0; k < 3; ++k) {
        int toff = t + (k - 1) * dil;
        bool valid = ((unsigned)toff < (unsigned)T);
        const float* Wk = Wl + k * C * 2 * C + ocb;
        for (int ic = 0; ic < C; ++ic) {
            float xv = valid ? (xb[(size_t)ic * T + toff] + cond_s[ic]) : 0.f;
            const float* wrow = Wk + ic * 2 * C;   // uniform address -> s_load
            #pragma unroll
            for (int oc = 0; oc < 64; ++oc) acc[oc] = fmaf(wrow[oc], xv, acc[oc]);
        }
    }

    // gating: wave1 holds filt (tanh), wave0 holds gate (sigmoid)
    if (w == 1) {
        #pragma unroll
        for (int ic = 0; ic < 64; ++ic) zs[ic][l] = tanhf(acc[ic]);
    }
    __syncthreads();
    if (w == 0) {
        #pragma unroll
        for (int ic = 0; ic < 64; ++ic) {
            float g = 1.f / (1.f + expf(-acc[ic]));
            zs[ic][l] *= g;
        }
    }
    __syncthreads();

    // 1x1 op conv: out channels [ocb, ocb+64)
    float acc2[64];
    const float* opb_l = op_b + layer * 2 * C;
    #pragma unroll
    for (int oc = 0; oc < 64; ++oc) acc2[oc] = opb_l[ocb + oc];
    const float* Ol = opT + (size_t)layer * C * 2 * C + ocb;
    for (int ic = 0; ic < C; ++ic) {
        float zv = zs[ic][l];
        const float* orow = Ol + ic * 2 * C;       // uniform -> s_load
        #pragma unroll
        for (int oc = 0; oc < 64; ++oc) acc2[oc] = fmaf(orow[oc], zv, acc2[oc]);
    }

    size_t base = (size_t)b * C * T + t;
    if (w == 0) {
        #pragma unroll
        for (int c2 = 0; c2 < 64; ++c2) {
            size_t p = base + (size_t)c2 * T;
            x_out[p] = (x_in[p] + acc2[c2]) * INV_SQRT2;
        }
    } else {
        #pragma unroll
        for (int c2 = 0; c2 < 64; ++c2) {
            size_t p = base + (size_t)c2 * T;
            skip[p] = first ? acc2[c2] : (skip[p] + acc2[c2]);
        }
    }
}

// ---------------------------------------------------------------------------
// Final: x = skip/sqrt(30); relu(conv1x1 sk_W) ; out = conv1x1 out_W + out_b
// One thread per (b,t).
// ---------------------------------------------------------------------------
__global__ void final_kernel(const float* __restrict__ skip,
                             const float* __restrict__ sk_W, const float* __restrict__ sk_b,
                             const float* __restrict__ out_W, const float* __restrict__ out_b,
                             float* __restrict__ out) {
    int idx = blockIdx.x * 256 + threadIdx.x; // over B*T
    int t = idx % T; int b = idx / T;
    const float* sb = skip + (size_t)b * C * T + t;
    float sv[64];
    #pragma unroll
    for (int ic = 0; ic < 64; ++ic) sv[ic] = sb[(size_t)ic * T] * INV_SQRT_NL;
    float o = out_b[0];
    for (int oc = 0; oc < 64; ++oc) {
        float a = sk_b[oc];
        const float* wrow = sk_W + oc * 64;        // uniform -> s_load
        #pragma unroll
        for (int ic = 0; ic < 64; ++ic) a = fmaf(wrow[ic], sv[ic], a);
        o = fmaf(out_W[oc], fmaxf(a, 0.f), o);
    }
    out[idx] = o;
}

// ---------------------------------------------------------------------------
extern "C" void kernel_launch(void* const* d_in, const int* in_sizes, int n_in,
                              void* d_out, int out_size, void* d_ws, size_t ws_size,
                              hipStream_t stream) {
    const float* audio = (const float*)d_in[0];
    const int*   dstep = (const int*)d_in[1];
    const float* in_W  = (const float*)d_in[2];
    const float* in_b  = (const float*)d_in[3];
    const float* p1_W  = (const float*)d_in[4];
    const float* p1_b  = (const float*)d_in[5];
    const float* p2_W  = (const float*)d_in[6];
    const float* p2_b  = (const float*)d_in[7];
    const float* dw_W  = (const float*)d_in[8];
    const float* dw_b  = (const float*)d_in[9];
    const float* dp_W  = (const float*)d_in[10];
    const float* dp_b  = (const float*)d_in[11];
    const float* op_W  = (const float*)d_in[12];
    const float* op_b  = (const float*)d_in[13];
    const float* sk_W  = (const float*)d_in[14];
    const float* sk_b  = (const float*)d_in[15];
    const float* out_W = (const float*)d_in[16];
    const float* out_b = (const float*)d_in[17];

    float* ws = (float*)d_ws;
    const size_t NX = (size_t)B * C * T;           // 4,194,304 floats
    float* xA   = ws;
    float* xB   = ws + NX;
    float* skip = ws + 2 * NX;
    float* cond = ws + 3 * NX;                     // NL*B*C = 7680
    float* dwT  = cond + NL * B * C;               // 737280
    float* opT  = dwT + NL * 3 * C * 2 * C;        // 245760

    hipLaunchKernelGGL(transpose_weights, dim3(3840), dim3(256), 0, stream,
                       dw_W, op_W, dwT, opT);
    hipLaunchKernelGGL(cond_kernel, dim3(B), dim3(256), 0, stream,
                       dstep, p1_W, p1_b, p2_W, p2_b, dp_W, dp_b, cond);
    hipLaunchKernelGGL(in_conv, dim3((B * C * T) / 256), dim3(256), 0, stream,
                       audio, in_W, in_b, xA);
    for (int i = 0; i < NL; ++i) {
        float* xin  = (i & 1) ? xB : xA;
        float* xout = (i & 1) ? xA : xB;
        int dil = 1 << (i % 10);
        hipLaunchKernelGGL(layer_kernel, dim3(T / 64, B), dim3(128), 0, stream,
                           xin, xout, skip, dwT, opT, dw_b, op_b, cond, i, dil,
                           (i == 0) ? 1 : 0);
    }
    hipLaunchKernelGGL(final_kernel, dim3((B * T) / 256), dim3(256), 0, stream,
                       skip, sk_W, sk_b, out_W, out_b, (float*)d_out);
}

// Round 2
// 3241.121 us; speedup vs baseline: 1.6050x; 1.6050x over previous
//
#include <hip/hip_runtime.h>
#include <math.h>

#define C 64
#define NL 30
#define T 16384
#define B 4

constexpr float INV_SQRT2 = 0.70710678118654752440f;
constexpr float INV_SQRT_NL = 0.18257418583505537115f; // 1/sqrt(30)

// ---------------------------------------------------------------------------
// Transpose weights to oc-contiguous layouts so per-layer weight reads are
// wave-uniform (scalar s_load) in the layer kernel.
//   dwT[l][k][ic][oc]  <- dw_W[l][oc][ic][k]
//   opT[l][ic][oc]     <- op_W[l][oc][ic]
// ---------------------------------------------------------------------------
__global__ void transpose_weights(const float* __restrict__ dw_W,
                                  const float* __restrict__ op_W,
                                  float* __restrict__ dwT,
                                  float* __restrict__ opT) {
    int idx = blockIdx.x * 256 + threadIdx.x;
    const int ndw = NL * 2 * C * C * 3;   // 737280
    const int nop = NL * 2 * C * C;       // 245760
    if (idx < ndw) {
        int k = idx % 3; int r = idx / 3;
        int ic = r % C; r /= C;
        int oc = r % (2 * C); int l = r / (2 * C);
        dwT[((l * 3 + k) * C + ic) * (2 * C) + oc] = dw_W[idx];
    } else if (idx < ndw + nop) {
        int j = idx - ndw;
        int ic = j % C; int r = j / C;
        int oc = r % (2 * C); int l = r / (2 * C);
        opT[(l * C + ic) * (2 * C) + oc] = op_W[j];
    }
}

// ---------------------------------------------------------------------------
// Cond stage 1: embedding -> p1 -> p2. One block per batch. h2out: [B][512]
// ---------------------------------------------------------------------------
__global__ void cond_stage1(const int* __restrict__ step,
                            const float* __restrict__ p1_W, const float* __restrict__ p1_b,
                            const float* __restrict__ p2_W, const float* __restrict__ p2_b,
                            float* __restrict__ h2out) {
    __shared__ float e[128];
    __shared__ float h1[512];
    int b = blockIdx.x;
    int tid = threadIdx.x;
    int s = step[b];
    if (tid < 128) {
        int d = tid & 63;
        float tf = (float)s * powf(10.f, (float)d * 4.f / 63.f);
        double td = (double)tf;
        e[tid] = (tid < 64) ? (float)sin(td) : (float)cos(td);
    }
    __syncthreads();
    for (int o = tid; o < 512; o += 256) {
        float a = p1_b[o];
        const float* wrow = p1_W + o * 128;
        for (int j = 0; j < 128; ++j) a = fmaf(e[j], wrow[j], a);
        h1[o] = a / (1.f + expf(-a));
    }
    __syncthreads();
    for (int o = tid; o < 512; o += 256) {
        float a = p2_b[o];
        const float* wrow = p2_W + o * 512;
        for (int j = 0; j < 512; ++j) a = fmaf(h1[j], wrow[j], a);
        h2out[b * 512 + o] = a / (1.f + expf(-a));
    }
}

// ---------------------------------------------------------------------------
// Cond stage 2: per-layer projections. grid (NL, B). 4 threads per output.
// cond layout: [NL][B][C]
// ---------------------------------------------------------------------------
__global__ void cond_stage2(const float* __restrict__ h2,
                            const float* __restrict__ dp_W, const float* __restrict__ dp_b,
                            float* __restrict__ cond) {
    __shared__ float part[256];
    int l = blockIdx.x, b = blockIdx.y;
    int tid = threadIdx.x;
    int o = tid >> 2, q = tid & 3;
    const float* wrow = dp_W + ((size_t)l * C + o) * 512 + q * 128;
    const float* h = h2 + b * 512 + q * 128;
    float a = 0.f;
    for (int j = 0; j < 128; ++j) a = fmaf(h[j], wrow[j], a);
    part[tid] = a;
    __syncthreads();
    if (q == 0) {
        cond[(l * B + b) * C + o] =
            part[tid] + part[tid + 1] + part[tid + 2] + part[tid + 3] + dp_b[l * C + o];
    }
}

// ---------------------------------------------------------------------------
// Input 1x1 conv + ReLU
// ---------------------------------------------------------------------------
__global__ void in_conv(const float* __restrict__ audio,
                        const float* __restrict__ in_W, const float* __restrict__ in_b,
                        float* __restrict__ x) {
    int idx = blockIdx.x * 256 + threadIdx.x;
    int t = idx % T; int r = idx / T; int c = r % C; int b = r / C;
    float v = fmaf(in_W[c], audio[b * T + t], in_b[c]);
    x[idx] = fmaxf(v, 0.f);
}

// ---------------------------------------------------------------------------
// One residual layer, fused. 256 threads = 4 waves. Wave w owns output
// channels [w*32, w*32+32) of the 2C=128 conv outputs -> acc[32] per lane
// (fits in VGPRs, no scratch). Lane owns t = blockIdx.x*64 + lane.
//   waves 0,1 = gate channels 0..63 ; waves 2,3 = filt channels 0..63
// ---------------------------------------------------------------------------
__global__ __launch_bounds__(256) void layer_kernel(
    const float* __restrict__ x_in, float* __restrict__ x_out, float* __restrict__ skip,
    const float* __restrict__ dwT, const float* __restrict__ opT,
    const float* __restrict__ dw_b, const float* __restrict__ op_b,
    const float* __restrict__ cond, int layer, int dil, int first)
{
    __shared__ float zs[C][64];
    __shared__ float cond_s[C];
    int b = blockIdx.y;
    int t0 = blockIdx.x * 64;
    int tid = threadIdx.x;
    int w = __builtin_amdgcn_readfirstlane(tid >> 6);   // wave id, uniform
    int l = tid & 63;
    int t = t0 + l;
    if (tid < C) cond_s[tid] = cond[(layer * B + b) * C + tid];
    __syncthreads();

    const float* xb = x_in + (size_t)b * C * T;
    int ocb = w * 32;

    float acc[32];
    const float* dwb_l = dw_b + layer * 2 * C + ocb;
    #pragma unroll
    for (int oc = 0; oc < 32; ++oc) acc[oc] = dwb_l[oc];

    const float* Wl = dwT + (size_t)layer * 3 * C * 2 * C + ocb;
    for (int k = 0; k < 3; ++k) {
        int toff = t + (k - 1) * dil;
        bool valid = ((unsigned)toff < (unsigned)T);
        const float* Wk = Wl + k * C * 2 * C;
        for (int ic = 0; ic < C; ++ic) {
            float xv = valid ? (xb[(size_t)ic * T + toff] + cond_s[ic]) : 0.f;
            const float* wrow = Wk + ic * 2 * C;   // uniform -> s_load
            #pragma unroll
            for (int oc = 0; oc < 32; ++oc) acc[oc] = fmaf(wrow[oc], xv, acc[oc]);
        }
    }

    // gating: waves 2,3 (filt) write tanh; waves 0,1 (gate) multiply sigmoid
    if (w >= 2) {
        int cb = ocb - C;
        #pragma unroll
        for (int i = 0; i < 32; ++i) zs[cb + i][l] = tanhf(acc[i]);
    }
    __syncthreads();
    if (w < 2) {
        #pragma unroll
        for (int i = 0; i < 32; ++i) {
            float g = 1.f / (1.f + expf(-acc[i]));
            zs[ocb + i][l] *= g;
        }
    }
    __syncthreads();

    // 1x1 op conv: out channels [ocb, ocb+32)
    float acc2[32];
    const float* opb_l = op_b + layer * 2 * C + ocb;
    #pragma unroll
    for (int oc = 0; oc < 32; ++oc) acc2[oc] = opb_l[oc];
    const float* Ol = opT + (size_t)layer * C * 2 * C + ocb;
    for (int ic = 0; ic < C; ++ic) {
        float zv = zs[ic][l];
        const float* orow = Ol + ic * 2 * C;       // uniform -> s_load
        #pragma unroll
        for (int oc = 0; oc < 32; ++oc) acc2[oc] = fmaf(orow[oc], zv, acc2[oc]);
    }

    size_t base = (size_t)b * C * T + t;
    if (w < 2) {
        // residual channels [ocb, ocb+32)
        #pragma unroll
        for (int i = 0; i < 32; ++i) {
            size_t p = base + (size_t)(ocb + i) * T;
            x_out[p] = (x_in[p] + acc2[i]) * INV_SQRT2;
        }
    } else {
        // skip channels [ocb-C, ocb-C+32)
        #pragma unroll
        for (int i = 0; i < 32; ++i) {
            size_t p = base + (size_t)(ocb - C + i) * T;
            skip[p] = first ? acc2[i] : (skip[p] + acc2[i]);
        }
    }
}

// ---------------------------------------------------------------------------
// Final: x = skip/sqrt(30); relu(conv1x1 sk_W); out = conv1x1 out_W + out_b
// ---------------------------------------------------------------------------
__global__ void final_kernel(const float* __restrict__ skip,
                             const float* __restrict__ sk_W, const float* __restrict__ sk_b,
                             const float* __restrict__ out_W, const float* __restrict__ out_b,
                             float* __restrict__ out) {
    int idx = blockIdx.x * 256 + threadIdx.x; // over B*T
    int t = idx % T; int b = idx / T;
    const float* sb = skip + (size_t)b * C * T + t;
    float sv[64];
    #pragma unroll
    for (int ic = 0; ic < 64; ++ic) sv[ic] = sb[(size_t)ic * T] * INV_SQRT_NL;
    float o = out_b[0];
    for (int oc = 0; oc < 64; ++oc) {
        float a = sk_b[oc];
        const float* wrow = sk_W + oc * 64;        // uniform -> s_load
        #pragma unroll
        for (int ic = 0; ic < 64; ++ic) a = fmaf(wrow[ic], sv[ic], a);
        o = fmaf(out_W[oc], fmaxf(a, 0.f), o);
    }
    out[idx] = o;
}

// ---------------------------------------------------------------------------
extern "C" void kernel_launch(void* const* d_in, const int* in_sizes, int n_in,
                              void* d_out, int out_size, void* d_ws, size_t ws_size,
                              hipStream_t stream) {
    const float* audio = (const float*)d_in[0];
    const int*   dstep = (const int*)d_in[1];
    const float* in_W  = (const float*)d_in[2];
    const float* in_b  = (const float*)d_in[3];
    const float* p1_W  = (const float*)d_in[4];
    const float* p1_b  = (const float*)d_in[5];
    const float* p2_W  = (const float*)d_in[6];
    const float* p2_b  = (const float*)d_in[7];
    const float* dw_W  = (const float*)d_in[8];
    const float* dw_b  = (const float*)d_in[9];
    const float* dp_W  = (const float*)d_in[10];
    const float* dp_b  = (const float*)d_in[11];
    const float* op_W  = (const float*)d_in[12];
    const float* op_b  = (const float*)d_in[13];
    const float* sk_W  = (const float*)d_in[14];
    const float* sk_b  = (const float*)d_in[15];
    const float* out_W = (const float*)d_in[16];
    const float* out_b = (const float*)d_in[17];

    float* ws = (float*)d_ws;
    const size_t NX = (size_t)B * C * T;           // 4,194,304 floats
    float* xA   = ws;
    float* xB   = ws + NX;
    float* skip = ws + 2 * NX;
    float* cond = ws + 3 * NX;                     // NL*B*C = 7680
    float* dwT  = cond + NL * B * C;               // 737280
    float* opT  = dwT + NL * 3 * C * 2 * C;        // 245760
    float* h2   = opT + NL * C * 2 * C;            // B*512

    hipLaunchKernelGGL(transpose_weights, dim3(3840), dim3(256), 0, stream,
                       dw_W, op_W, dwT, opT);
    hipLaunchKernelGGL(cond_stage1, dim3(B), dim3(256), 0, stream,
                       dstep, p1_W, p1_b, p2_W, p2_b, h2);
    hipLaunchKernelGGL(cond_stage2, dim3(NL, B), dim3(256), 0, stream,
                       h2, dp_W, dp_b, cond);
    hipLaunchKernelGGL(in_conv, dim3((B * C * T) / 256), dim3(256), 0, stream,
                       audio, in_W, in_b, xA);
    for (int i = 0; i < NL; ++i) {
        float* xin  = (i & 1) ? xB : xA;
        float* xout = (i & 1) ? xA : xB;
        int dil = 1 << (i % 10);
        hipLaunchKernelGGL(layer_kernel, dim3(T / 64, B), dim3(256), 0, stream,
                           xin, xout, skip, dwT, opT, dw_b, op_b, cond, i, dil,
                           (i == 0) ? 1 : 0);
    }
    hipLaunchKernelGGL(final_kernel, dim3((B * T) / 256), dim3(256), 0, stream,
                       skip, sk_W, sk_b, out_W, out_b, (float*)d_out);
}

// Round 3
// 1283.594 us; speedup vs baseline: 4.0526x; 2.5250x over previous
//
#include <hip/hip_runtime.h>
#include <math.h>

#define C 64
#define NL 30
#define T 16384
#define B 4

typedef __bf16 bf16_t;
typedef __bf16 bf16x8 __attribute__((ext_vector_type(8)));
typedef float f32x4 __attribute__((ext_vector_type(4)));

constexpr float INV_SQRT2   = 0.70710678118654752440f;
constexpr float INV_SQRT_NL = 0.18257418583505537115f; // 1/sqrt(30)

__device__ __forceinline__ float fsig(float x) {
    return __builtin_amdgcn_rcpf(1.f + __builtin_amdgcn_exp2f(-1.44269504089f * x));
}
__device__ __forceinline__ float ftanh(float x) {
    // tanh(x) = 2*sigmoid(2x) - 1
    return fmaf(2.f, __builtin_amdgcn_rcpf(1.f + __builtin_amdgcn_exp2f(-2.88539008178f * x)), -1.f);
}
// XOR swizzle for 128-byte-row LDS tiles (G4): byte ^= ((row&7)<<4)
__device__ __forceinline__ int swz(int off) { return off ^ ((off >> 3) & 0x70); }

// ---------------------------------------------------------------------------
// Pack weights to bf16, K-contiguous rows:
//   convpk[l][oc][k] , k = tap*64 + ic  (k in [0,192))
//   oppk  [l][oc][ic]                    (same layout as op_W, just bf16)
// ---------------------------------------------------------------------------
__global__ void pack_weights(const float* __restrict__ dw_W,
                             const float* __restrict__ op_W,
                             bf16_t* __restrict__ convpk,
                             bf16_t* __restrict__ oppk) {
    int idx = blockIdx.x * 256 + threadIdx.x;
    const int ndw = NL * 128 * 192;
    const int nop = NL * 128 * 64;
    if (idx < ndw) {
        int k = idx % 192; int r = idx / 192;
        int oc = r % 128;  int l = r / 128;
        int tap = k >> 6, ic = k & 63;
        convpk[idx] = (bf16_t)dw_W[((l * 128 + oc) * 64 + ic) * 3 + tap];
    } else if (idx < ndw + nop) {
        int j = idx - ndw;
        oppk[j] = (bf16_t)op_W[j];
    }
}

// ---------------------------------------------------------------------------
// Cond stage 1: embedding -> p1(silu) -> p2(silu). One block/batch, 512 thr.
// ---------------------------------------------------------------------------
__global__ void cond_stage1(const int* __restrict__ step,
                            const float* __restrict__ p1_W, const float* __restrict__ p1_b,
                            const float* __restrict__ p2_W, const float* __restrict__ p2_b,
                            float* __restrict__ h2out) {
    __shared__ float e[128];
    __shared__ float h1[512];
    int b = blockIdx.x;
    int tid = threadIdx.x;
    int s = step[b];
    if (tid < 128) {
        int d = tid & 63;
        float tf = (float)s * powf(10.f, (float)d * 4.f / 63.f);
        double td = (double)tf;
        e[tid] = (tid < 64) ? (float)sin(td) : (float)cos(td);
    }
    __syncthreads();
    {
        int o = tid;
        float a = p1_b[o];
        const float4* wr = (const float4*)(p1_W + o * 128);
        #pragma unroll 8
        for (int j = 0; j < 32; ++j) {
            float4 wv = wr[j];
            float4 ev = *(const float4*)(e + j * 4);
            a = fmaf(wv.x, ev.x, a); a = fmaf(wv.y, ev.y, a);
            a = fmaf(wv.z, ev.z, a); a = fmaf(wv.w, ev.w, a);
        }
        h1[o] = a / (1.f + expf(-a));
    }
    __syncthreads();
    {
        int o = tid;
        float a = p2_b[o];
        const float4* wr = (const float4*)(p2_W + o * 512);
        #pragma unroll 8
        for (int j = 0; j < 128; ++j) {
            float4 wv = wr[j];
            float4 hv = *(const float4*)(h1 + j * 4);
            a = fmaf(wv.x, hv.x, a); a = fmaf(wv.y, hv.y, a);
            a = fmaf(wv.z, hv.z, a); a = fmaf(wv.w, hv.w, a);
        }
        h2out[b * 512 + o] = a / (1.f + expf(-a));
    }
}

// ---------------------------------------------------------------------------
// Cond stage 2: per-layer projections. grid (NL,B). 4 threads/output.
// ---------------------------------------------------------------------------
__global__ void cond_stage2(const float* __restrict__ h2,
                            const float* __restrict__ dp_W, const float* __restrict__ dp_b,
                            float* __restrict__ cond) {
    __shared__ float part[256];
    int l = blockIdx.x, b = blockIdx.y;
    int tid = threadIdx.x;
    int o = tid >> 2, q = tid & 3;
    const float4* wr = (const float4*)(dp_W + ((size_t)l * C + o) * 512 + q * 128);
    const float4* h = (const float4*)(h2 + b * 512 + q * 128);
    float a = 0.f;
    #pragma unroll 8
    for (int j = 0; j < 32; ++j) {
        float4 wv = wr[j]; float4 hv = h[j];
        a = fmaf(wv.x, hv.x, a); a = fmaf(wv.y, hv.y, a);
        a = fmaf(wv.z, hv.z, a); a = fmaf(wv.w, hv.w, a);
    }
    part[tid] = a;
    __syncthreads();
    if (q == 0) {
        cond[(l * B + b) * C + o] =
            part[tid] + part[tid + 1] + part[tid + 2] + part[tid + 3] + dp_b[l * C + o];
    }
}

// ---------------------------------------------------------------------------
// Input 1x1 conv + ReLU
// ---------------------------------------------------------------------------
__global__ void in_conv(const float* __restrict__ audio,
                        const float* __restrict__ in_W, const float* __restrict__ in_b,
                        float* __restrict__ x) {
    int idx = blockIdx.x * 256 + threadIdx.x;
    int t = idx % T; int r = idx / T; int c = r % C; int b = r / C;
    float v = fmaf(in_W[c], audio[b * T + t], in_b[c]);
    x[idx] = fmaxf(v, 0.f);
}

// ---------------------------------------------------------------------------
// One residual layer, MFMA version. 256 threads = 4 waves; 64-t tile.
// Wave w owns conv rows {w*16..+16} (gate, mf=0) and {64+w*16..+16} (filt,
// mf=1) -> gate/filt pair sits in the SAME lane/reg -> no exchange.
// LDS: xs[3][64 t][64 ic] bf16 (24KB, XOR-swizzled) + z[64 t][64 zc] (8KB).
// ---------------------------------------------------------------------------
__global__ __launch_bounds__(256) void layer_kernel(
    const float* __restrict__ x_in, float* __restrict__ x_out, float* __restrict__ skip,
    const bf16_t* __restrict__ convpk, const bf16_t* __restrict__ oppk,
    const float* __restrict__ dw_b, const float* __restrict__ op_b,
    const float* __restrict__ cond, int layer, int dil, int first)
{
    __shared__ uint4 smem_u[2048];                       // 32768 B
    unsigned char* sm = (unsigned char*)smem_u;

    int tid = threadIdx.x;
    int w = __builtin_amdgcn_readfirstlane(tid >> 6);    // wave id
    int l = tid & 63;
    int lr = l & 15;                                     // m/n row within frag
    int g = l >> 4;                                      // k-group
    int b = blockIdx.y;
    int t0 = blockIdx.x * 64;
    const float* xb = x_in + (size_t)b * C * T;

    // ---- A fragments (weights) held in registers -------------------------
    bf16x8 cA[2][6];
    const bf16_t* cw = convpk + (size_t)layer * 128 * 192;
    #pragma unroll
    for (int mf = 0; mf < 2; ++mf)
        #pragma unroll
        for (int kf = 0; kf < 6; ++kf)
            cA[mf][kf] = *(const bf16x8*)(cw + (mf * 64 + w * 16 + lr) * 192 + kf * 32 + g * 8);
    bf16x8 oA[2][2];
    const bf16_t* ow = oppk + (size_t)layer * 128 * 64;
    #pragma unroll
    for (int mf = 0; mf < 2; ++mf)
        #pragma unroll
        for (int kf = 0; kf < 2; ++kf)
            oA[mf][kf] = *(const bf16x8*)(ow + (mf * 64 + w * 16 + lr) * 64 + kf * 32 + g * 8);

    // ---- conv accumulators init with bias --------------------------------
    f32x4 acc[2][4];
    const float* db = dw_b + layer * 2 * C;
    #pragma unroll
    for (int mf = 0; mf < 2; ++mf) {
        f32x4 bv;
        #pragma unroll
        for (int r = 0; r < 4; ++r) bv[r] = db[mf * 64 + w * 16 + g * 4 + r];
        #pragma unroll
        for (int nf = 0; nf < 4; ++nf) acc[mf][nf] = bv;
    }

    float condv = cond[(layer * B + b) * C + l];

    // ---- stage xs = bf16(x + cond), 3 shifted slices, zero-padded --------
    // thread handles ic = l; iteration s = it*4+w covers (tap, t-group)
    #pragma unroll
    for (int it = 0; it < 12; ++it) {
        int s = it * 4 + w;                 // 0..47
        int tap = s >> 4;
        int tt = (s & 15) * 4;
        int ts = t0 + tt + (tap - 1) * dil;
        float v[4];
        if (tap == 1 || ((dil & 3) == 0 && ts >= 0 && ts + 3 < T)) {
            float4 f = *(const float4*)(xb + (size_t)l * T + ts);
            v[0] = f.x + condv; v[1] = f.y + condv; v[2] = f.z + condv; v[3] = f.w + condv;
        } else {
            #pragma unroll
            for (int u = 0; u < 4; ++u) {
                int tsu = ts + u;
                v[u] = ((unsigned)tsu < (unsigned)T) ? (xb[(size_t)l * T + tsu] + condv) : 0.f;
            }
        }
        #pragma unroll
        for (int u = 0; u < 4; ++u) {
            int off = tap * 8192 + (tt + u) * 128 + l * 2;
            *(bf16_t*)(sm + swz(off)) = (bf16_t)v[u];
        }
    }
    __syncthreads();

    // ---- conv GEMM: K = 3 taps x 64 ic = 6 k-frags -----------------------
    #pragma unroll
    for (int kf = 0; kf < 6; ++kf) {
        int tap = kf >> 1;
        int kc = (kf & 1) * 32;
        bf16x8 Bf[4];
        #pragma unroll
        for (int nf = 0; nf < 4; ++nf) {
            int off = tap * 8192 + (nf * 16 + lr) * 128 + (kc + g * 8) * 2;
            Bf[nf] = *(const bf16x8*)(sm + swz(off));
        }
        #pragma unroll
        for (int mf = 0; mf < 2; ++mf)
            #pragma unroll
            for (int nf = 0; nf < 4; ++nf)
                acc[mf][nf] = __builtin_amdgcn_mfma_f32_16x16x32_bf16(
                    cA[mf][kf], Bf[nf], acc[mf][nf], 0, 0, 0);
    }

    // ---- gating in-lane, write z to LDS in B-frag layout -----------------
    #pragma unroll
    for (int nf = 0; nf < 4; ++nf) {
        union { bf16_t h[4]; uint2 u; } zp;
        #pragma unroll
        for (int r = 0; r < 4; ++r) {
            float zv = fsig(acc[0][nf][r]) * ftanh(acc[1][nf][r]);
            zp.h[r] = (bf16_t)zv;
        }
        int off = 24576 + (nf * 16 + lr) * 128 + (w * 16 + g * 4) * 2;
        *(uint2*)(sm + swz(off)) = zp.u;
    }
    __syncthreads();

    // ---- op 1x1 GEMM: K = 64 = 2 k-frags ---------------------------------
    f32x4 acc2[2][4];
    const float* ob = op_b + layer * 2 * C;
    #pragma unroll
    for (int mf = 0; mf < 2; ++mf) {
        f32x4 bv;
        #pragma unroll
        for (int r = 0; r < 4; ++r) bv[r] = ob[mf * 64 + w * 16 + g * 4 + r];
        #pragma unroll
        for (int nf = 0; nf < 4; ++nf) acc2[mf][nf] = bv;
    }
    #pragma unroll
    for (int kf = 0; kf < 2; ++kf) {
        bf16x8 Zf[4];
        #pragma unroll
        for (int nf = 0; nf < 4; ++nf) {
            int off = 24576 + (nf * 16 + lr) * 128 + (kf * 32 + g * 8) * 2;
            Zf[nf] = *(const bf16x8*)(sm + swz(off));
        }
        #pragma unroll
        for (int mf = 0; mf < 2; ++mf)
            #pragma unroll
            for (int nf = 0; nf < 4; ++nf)
                acc2[mf][nf] = __builtin_amdgcn_mfma_f32_16x16x32_bf16(
                    oA[mf][kf], Zf[nf], acc2[mf][nf], 0, 0, 0);
    }

    // ---- epilogue: residual (mf=0) + skip accumulate (mf=1) --------------
    size_t bb = (size_t)b * C * T;
    #pragma unroll
    for (int nf = 0; nf < 4; ++nf) {
        int tcol = t0 + nf * 16 + lr;
        #pragma unroll
        for (int r = 0; r < 4; ++r) {
            int row = w * 16 + g * 4 + r;                // C/D: row=(lane>>4)*4+reg
            size_t p = bb + (size_t)row * T + tcol;
            x_out[p] = (x_in[p] + acc2[0][nf][r]) * INV_SQRT2;
            float sv = acc2[1][nf][r];
            skip[p] = first ? sv : (skip[p] + sv);
        }
    }
}

// ---------------------------------------------------------------------------
// Final: skip/sqrt(30) -> sk conv(64x64)+relu -> out conv (dot with out_W).
// Block per 64-t tile; LDS-staged skip tile; per-wave 16 sk rows.
// ---------------------------------------------------------------------------
__global__ __launch_bounds__(256) void final_kernel(
    const float* __restrict__ skip,
    const float* __restrict__ sk_W, const float* __restrict__ sk_b,
    const float* __restrict__ out_W, const float* __restrict__ out_b,
    float* __restrict__ out)
{
    __shared__ float sk_s[64][66];
    __shared__ float partial[4][64];
    int tid = threadIdx.x, w = tid >> 6, l = tid & 63;
    int b = blockIdx.y, t0 = blockIdx.x * 64;
    const float* sb = skip + (size_t)b * C * T + t0;
    #pragma unroll
    for (int it = 0; it < 4; ++it) {
        int s = it * 256 + tid;             // 0..1023
        int ic = s >> 4, tg = (s & 15) * 4;
        float4 f = *(const float4*)(sb + (size_t)ic * T + tg);
        sk_s[ic][tg + 0] = f.x * INV_SQRT_NL;
        sk_s[ic][tg + 1] = f.y * INV_SQRT_NL;
        sk_s[ic][tg + 2] = f.z * INV_SQRT_NL;
        sk_s[ic][tg + 3] = f.w * INV_SQRT_NL;
    }
    __syncthreads();
    float a[16];
    #pragma unroll
    for (int r = 0; r < 16; ++r) a[r] = sk_b[w * 16 + r];
    for (int ic = 0; ic < 64; ++ic) {
        float xv = sk_s[ic][l];
        #pragma unroll
        for (int r = 0; r < 16; ++r) a[r] = fmaf(sk_W[(w * 16 + r) * 64 + ic], xv, a[r]);
    }
    float o = 0.f;
    #pragma unroll
    for (int r = 0; r < 16; ++r) o = fmaf(out_W[w * 16 + r], fmaxf(a[r], 0.f), o);
    partial[w][l] = o;
    __syncthreads();
    if (w == 0)
        out[(size_t)b * T + t0 + l] =
            partial[0][l] + partial[1][l] + partial[2][l] + partial[3][l] + out_b[0];
}

// ---------------------------------------------------------------------------
extern "C" void kernel_launch(void* const* d_in, const int* in_sizes, int n_in,
                              void* d_out, int out_size, void* d_ws, size_t ws_size,
                              hipStream_t stream) {
    const float* audio = (const float*)d_in[0];
    const int*   dstep = (const int*)d_in[1];
    const float* in_W  = (const float*)d_in[2];
    const float* in_b  = (const float*)d_in[3];
    const float* p1_W  = (const float*)d_in[4];
    const float* p1_b  = (const float*)d_in[5];
    const float* p2_W  = (const float*)d_in[6];
    const float* p2_b  = (const float*)d_in[7];
    const float* dw_W  = (const float*)d_in[8];
    const float* dw_b  = (const float*)d_in[9];
    const float* dp_W  = (const float*)d_in[10];
    const float* dp_b  = (const float*)d_in[11];
    const float* op_W  = (const float*)d_in[12];
    const float* op_b  = (const float*)d_in[13];
    const float* sk_W  = (const float*)d_in[14];
    const float* sk_b  = (const float*)d_in[15];
    const float* out_W = (const float*)d_in[16];
    const float* out_b = (const float*)d_in[17];

    float* ws = (float*)d_ws;
    const size_t NX = (size_t)B * C * T;            // 4,194,304 floats
    float* xA   = ws;
    float* xB   = ws + NX;
    float* skip = ws + 2 * NX;
    float* cond = ws + 3 * NX;                      // NL*B*C = 7680
    float* h2   = cond + NL * B * C;                // 2048
    bf16_t* convpk = (bf16_t*)(h2 + B * 512);       // NL*128*192 bf16
    bf16_t* oppk   = convpk + NL * 128 * 192;       // NL*128*64 bf16

    hipLaunchKernelGGL(pack_weights, dim3(3840), dim3(256), 0, stream,
                       dw_W, op_W, convpk, oppk);
    hipLaunchKernelGGL(cond_stage1, dim3(B), dim3(512), 0, stream,
                       dstep, p1_W, p1_b, p2_W, p2_b, h2);
    hipLaunchKernelGGL(cond_stage2, dim3(NL, B), dim3(256), 0, stream,
                       h2, dp_W, dp_b, cond);
    hipLaunchKernelGGL(in_conv, dim3((B * C * T) / 256), dim3(256), 0, stream,
                       audio, in_W, in_b, xA);
    for (int i = 0; i < NL; ++i) {
        float* xin  = (i & 1) ? xB : xA;
        float* xout = (i & 1) ? xA : xB;
        int dil = 1 << (i % 10);
        hipLaunchKernelGGL(layer_kernel, dim3(T / 64, B), dim3(256), 0, stream,
                           xin, xout, skip, convpk, oppk, dw_b, op_b, cond, i, dil,
                           (i == 0) ? 1 : 0);
    }
    hipLaunchKernelGGL(final_kernel, dim3(T / 64, B), dim3(256), 0, stream,
                       skip, sk_W, sk_b, out_W, out_b, (float*)d_out);
}

// Round 4
// 673.773 us; speedup vs baseline: 7.7205x; 1.9051x over previous
//
#include <hip/hip_runtime.h>
#include <math.h>

#define C 64
#define NL 30
#define T 16384
#define B 4

typedef __bf16 bf16_t;
typedef __bf16 bf16x8 __attribute__((ext_vector_type(8)));
typedef __bf16 bf16x4 __attribute__((ext_vector_type(4)));
typedef float f32x4 __attribute__((ext_vector_type(4)));

constexpr float INV_SQRT2   = 0.70710678118654752440f;
constexpr float INV_SQRT_NL = 0.18257418583505537115f; // 1/sqrt(30)

__device__ __forceinline__ float fsig(float x) {
    return __builtin_amdgcn_rcpf(1.f + __builtin_amdgcn_exp2f(-1.44269504089f * x));
}
__device__ __forceinline__ float ftanh(float x) {
    return fmaf(2.f, __builtin_amdgcn_rcpf(1.f + __builtin_amdgcn_exp2f(-2.88539008178f * x)), -1.f);
}
// XOR swizzle for 128-byte-row LDS tiles (G4): byte ^= ((row&7)<<4)
__device__ __forceinline__ int swz(int off) { return off ^ ((off >> 3) & 0x70); }

// ---------------------------------------------------------------------------
// Pack weights to bf16 K-contiguous rows:
//   convpk[l][oc][k], k = tap*64+ic ; oppk[l][oc][ic] ; skpk[oc][ic]*1/sqrt(30)
// ---------------------------------------------------------------------------
__global__ void pack_weights(const float* __restrict__ dw_W,
                             const float* __restrict__ op_W,
                             const float* __restrict__ sk_W,
                             bf16_t* __restrict__ convpk,
                             bf16_t* __restrict__ oppk,
                             bf16_t* __restrict__ skpk) {
    int idx = blockIdx.x * 256 + threadIdx.x;
    const int ndw = NL * 128 * 192;
    const int nop = NL * 128 * 64;
    if (idx < ndw) {
        int k = idx % 192; int r = idx / 192;
        int oc = r % 128;  int l = r / 128;
        int tap = k >> 6, ic = k & 63;
        convpk[idx] = (bf16_t)dw_W[((l * 128 + oc) * 64 + ic) * 3 + tap];
    } else if (idx < ndw + nop) {
        oppk[idx - ndw] = (bf16_t)op_W[idx - ndw];
    } else if (idx < ndw + nop + 4096) {
        int j = idx - ndw - nop;
        skpk[j] = (bf16_t)(sk_W[j] * INV_SQRT_NL);
    }
}

// ---------------------------------------------------------------------------
// Cond stage 1: embedding -> p1(silu) -> p2(silu). One block/batch, 512 thr.
// ---------------------------------------------------------------------------
__global__ void cond_stage1(const int* __restrict__ step,
                            const float* __restrict__ p1_W, const float* __restrict__ p1_b,
                            const float* __restrict__ p2_W, const float* __restrict__ p2_b,
                            float* __restrict__ h2out) {
    __shared__ float e[128];
    __shared__ float h1[512];
    int b = blockIdx.x;
    int tid = threadIdx.x;
    int s = step[b];
    if (tid < 128) {
        int d = tid & 63;
        float tf = (float)s * powf(10.f, (float)d * 4.f / 63.f);
        double td = (double)tf;
        e[tid] = (tid < 64) ? (float)sin(td) : (float)cos(td);
    }
    __syncthreads();
    {
        int o = tid;
        float a = p1_b[o];
        const float4* wr = (const float4*)(p1_W + o * 128);
        #pragma unroll 8
        for (int j = 0; j < 32; ++j) {
            float4 wv = wr[j];
            float4 ev = *(const float4*)(e + j * 4);
            a = fmaf(wv.x, ev.x, a); a = fmaf(wv.y, ev.y, a);
            a = fmaf(wv.z, ev.z, a); a = fmaf(wv.w, ev.w, a);
        }
        h1[o] = a / (1.f + expf(-a));
    }
    __syncthreads();
    {
        int o = tid;
        float a = p2_b[o];
        const float4* wr = (const float4*)(p2_W + o * 512);
        #pragma unroll 8
        for (int j = 0; j < 128; ++j) {
            float4 wv = wr[j];
            float4 hv = *(const float4*)(h1 + j * 4);
            a = fmaf(wv.x, hv.x, a); a = fmaf(wv.y, hv.y, a);
            a = fmaf(wv.z, hv.z, a); a = fmaf(wv.w, hv.w, a);
        }
        h2out[b * 512 + o] = a / (1.f + expf(-a));
    }
}

// ---------------------------------------------------------------------------
// Cond stage 2: cond[l][b][c] = dp_W[l] @ h2[b] + dp_b[l]
// ---------------------------------------------------------------------------
__global__ void cond_stage2(const float* __restrict__ h2,
                            const float* __restrict__ dp_W, const float* __restrict__ dp_b,
                            float* __restrict__ cond) {
    __shared__ float part[256];
    int l = blockIdx.x, b = blockIdx.y;
    int tid = threadIdx.x;
    int o = tid >> 2, q = tid & 3;
    const float4* wr = (const float4*)(dp_W + ((size_t)l * C + o) * 512 + q * 128);
    const float4* h = (const float4*)(h2 + b * 512 + q * 128);
    float a = 0.f;
    #pragma unroll 8
    for (int j = 0; j < 32; ++j) {
        float4 wv = wr[j]; float4 hv = h[j];
        a = fmaf(wv.x, hv.x, a); a = fmaf(wv.y, hv.y, a);
        a = fmaf(wv.z, hv.z, a); a = fmaf(wv.w, hv.w, a);
    }
    part[tid] = a;
    __syncthreads();
    if (q == 0) {
        cond[(l * B + b) * C + o] =
            part[tid] + part[tid + 1] + part[tid + 2] + part[tid + 3] + dp_b[l * C + o];
    }
}

// ---------------------------------------------------------------------------
// Fold cond into conv bias: bias2[l][b][oc] = dw_b[l][oc] + sum_k W[oc][k]*cond[k&63]
// (uses the SAME bf16-rounded weights as the GEMM, so folding is consistent)
// ---------------------------------------------------------------------------
__global__ void cond_fold(const bf16_t* __restrict__ convpk,
                          const float* __restrict__ dw_b,
                          const float* __restrict__ cond,
                          float* __restrict__ bias2) {
    int l = blockIdx.x, b = blockIdx.y;
    int oc = threadIdx.x;                      // 128 threads
    const bf16_t* wr = convpk + ((size_t)l * 128 + oc) * 192;
    const float* cd = cond + (l * B + b) * C;
    float a = dw_b[l * 128 + oc];
    #pragma unroll 3
    for (int tap = 0; tap < 3; ++tap) {
        #pragma unroll
        for (int ic = 0; ic < 64; ++ic)
            a = fmaf((float)wr[tap * 64 + ic], cd[ic], a);
    }
    bias2[(l * B + b) * 128 + oc] = a;
}

// ---------------------------------------------------------------------------
// Input 1x1 conv + ReLU -> x[b][t][c] bf16. Thread handles 8 channels.
// ---------------------------------------------------------------------------
__global__ void in_conv(const float* __restrict__ audio,
                        const float* __restrict__ in_W, const float* __restrict__ in_b,
                        bf16_t* __restrict__ x) {
    int idx = blockIdx.x * 256 + threadIdx.x;   // over B*T*8
    int cb = idx & 7;
    int t = (idx >> 3) & (T - 1);
    int b = idx >> 17;
    float av = audio[b * T + t];
    bf16x8 o;
    #pragma unroll
    for (int j = 0; j < 8; ++j) {
        int c = cb * 8 + j;
        o[j] = (bf16_t)fmaxf(fmaf(in_W[c], av, in_b[c]), 0.f);
    }
    *(bf16x8*)(x + ((size_t)b * T + t) * 64 + cb * 8) = o;
}

// ---------------------------------------------------------------------------
// One residual layer. x layout [b][t][c] bf16. 256 thr = 4 waves, 64-t tile.
// Wave w owns conv rows {w*16..+16} (gate) and {64+w*16..+16} (filt): the
// gate/filt pair sits in the same lane/reg -> gating needs no exchange.
// LDS: 3 tap slices [64t][64c] bf16 (24KB) + z tile [64t][64c] (8KB), swizzled.
// ---------------------------------------------------------------------------
__global__ __launch_bounds__(256) void layer_kernel(
    const bf16_t* __restrict__ x_in, bf16_t* __restrict__ x_out, bf16_t* __restrict__ skip,
    const bf16_t* __restrict__ convpk, const bf16_t* __restrict__ oppk,
    const float* __restrict__ bias2, const float* __restrict__ op_b,
    int layer, int dil, int first)
{
    __shared__ uint4 smem_u[2048];                       // 32768 B
    unsigned char* sm = (unsigned char*)smem_u;

    int tid = threadIdx.x;
    int w = __builtin_amdgcn_readfirstlane(tid >> 6);
    int l = tid & 63;
    int lr = l & 15;
    int g = l >> 4;
    int b = blockIdx.y;
    int t0 = blockIdx.x * 64;
    const bf16_t* xb = x_in + (size_t)b * T * 64;

    // ---- A fragments (weights) in registers ------------------------------
    bf16x8 cA[2][6];
    const bf16_t* cw = convpk + (size_t)layer * 128 * 192;
    #pragma unroll
    for (int mf = 0; mf < 2; ++mf)
        #pragma unroll
        for (int kf = 0; kf < 6; ++kf)
            cA[mf][kf] = *(const bf16x8*)(cw + (mf * 64 + w * 16 + lr) * 192 + kf * 32 + g * 8);
    bf16x8 oA[2][2];
    const bf16_t* ow = oppk + (size_t)layer * 128 * 64;
    #pragma unroll
    for (int mf = 0; mf < 2; ++mf)
        #pragma unroll
        for (int kf = 0; kf < 2; ++kf)
            oA[mf][kf] = *(const bf16x8*)(ow + (mf * 64 + w * 16 + lr) * 64 + kf * 32 + g * 8);

    // ---- stage raw x tile (cond folded into bias): 6 x 16B per thread ----
    #pragma unroll
    for (int it = 0; it < 6; ++it) {
        int q = it * 256 + tid;             // 0..1535
        int slice = q >> 9;
        int row = (q >> 3) & 63;
        int c16 = q & 7;
        int ts = t0 + row + (slice - 1) * dil;
        uint4 val = make_uint4(0u, 0u, 0u, 0u);
        if ((unsigned)ts < (unsigned)T)
            val = *(const uint4*)(xb + (size_t)ts * 64 + c16 * 8);
        *(uint4*)(sm + swz(slice * 8192 + row * 128 + c16 * 16)) = val;
    }

    // ---- conv accumulators init with cond-folded bias --------------------
    f32x4 acc[2][4];
    const float* b2 = bias2 + (layer * B + b) * 128;
    #pragma unroll
    for (int mf = 0; mf < 2; ++mf) {
        f32x4 bv;
        #pragma unroll
        for (int r = 0; r < 4; ++r) bv[r] = b2[mf * 64 + w * 16 + g * 4 + r];
        #pragma unroll
        for (int nf = 0; nf < 4; ++nf) acc[mf][nf] = bv;
    }
    __syncthreads();

    // ---- conv GEMM: K = 3 taps x 64 c ------------------------------------
    #pragma unroll
    for (int kf = 0; kf < 6; ++kf) {
        int tap = kf >> 1;
        int kc = (kf & 1) * 32;
        bf16x8 Bf[4];
        #pragma unroll
        for (int nf = 0; nf < 4; ++nf) {
            int off = tap * 8192 + (nf * 16 + lr) * 128 + (kc + g * 8) * 2;
            Bf[nf] = *(const bf16x8*)(sm + swz(off));
        }
        #pragma unroll
        for (int mf = 0; mf < 2; ++mf)
            #pragma unroll
            for (int nf = 0; nf < 4; ++nf)
                acc[mf][nf] = __builtin_amdgcn_mfma_f32_16x16x32_bf16(
                    cA[mf][kf], Bf[nf], acc[mf][nf], 0, 0, 0);
    }

    // ---- gating in-lane, z -> LDS in B-frag layout -----------------------
    #pragma unroll
    for (int nf = 0; nf < 4; ++nf) {
        union { bf16_t h[4]; uint2 u; } zp;
        #pragma unroll
        for (int r = 0; r < 4; ++r)
            zp.h[r] = (bf16_t)(fsig(acc[0][nf][r]) * ftanh(acc[1][nf][r]));
        int off = 24576 + (nf * 16 + lr) * 128 + (w * 16 + g * 4) * 2;
        *(uint2*)(sm + swz(off)) = zp.u;
    }
    __syncthreads();

    // ---- op 1x1 GEMM ------------------------------------------------------
    f32x4 acc2[2][4];
    const float* ob = op_b + layer * 2 * C;
    #pragma unroll
    for (int mf = 0; mf < 2; ++mf) {
        f32x4 bv;
        #pragma unroll
        for (int r = 0; r < 4; ++r) bv[r] = ob[mf * 64 + w * 16 + g * 4 + r];
        #pragma unroll
        for (int nf = 0; nf < 4; ++nf) acc2[mf][nf] = bv;
    }
    #pragma unroll
    for (int kf = 0; kf < 2; ++kf) {
        bf16x8 Zf[4];
        #pragma unroll
        for (int nf = 0; nf < 4; ++nf) {
            int off = 24576 + (nf * 16 + lr) * 128 + (kf * 32 + g * 8) * 2;
            Zf[nf] = *(const bf16x8*)(sm + swz(off));
        }
        #pragma unroll
        for (int mf = 0; mf < 2; ++mf)
            #pragma unroll
            for (int nf = 0; nf < 4; ++nf)
                acc2[mf][nf] = __builtin_amdgcn_mfma_f32_16x16x32_bf16(
                    oA[mf][kf], Zf[nf], acc2[mf][nf], 0, 0, 0);
    }

    // ---- epilogue: residual + skip, [t][c] bf16, 8B per lane per nf ------
    size_t bb = (size_t)b * T * 64;
    #pragma unroll
    for (int nf = 0; nf < 4; ++nf) {
        int t = t0 + nf * 16 + lr;
        int c0 = w * 16 + g * 4;
        // x_in from LDS tap-1 slice
        int xoff = 8192 + (nf * 16 + lr) * 128 + c0 * 2;
        bf16x4 xv = *(const bf16x4*)(sm + swz(xoff));
        bf16x4 ro, so;
        bf16_t* sp = skip + bb + (size_t)t * 64 + c0;
        if (first) {
            #pragma unroll
            for (int r = 0; r < 4; ++r) {
                ro[r] = (bf16_t)(((float)xv[r] + acc2[0][nf][r]) * INV_SQRT2);
                so[r] = (bf16_t)acc2[1][nf][r];
            }
        } else {
            bf16x4 sv = *(const bf16x4*)sp;
            #pragma unroll
            for (int r = 0; r < 4; ++r) {
                ro[r] = (bf16_t)(((float)xv[r] + acc2[0][nf][r]) * INV_SQRT2);
                so[r] = (bf16_t)((float)sv[r] + acc2[1][nf][r]);
            }
        }
        *(bf16x4*)(x_out + bb + (size_t)t * 64 + c0) = ro;
        *(bf16x4*)sp = so;
    }
}

// ---------------------------------------------------------------------------
// Final: skip(bf16,[t][c]) -> sk conv (MFMA, weights pre-scaled by 1/sqrt30)
// -> relu -> dot with out_W + out_b. Block = 64-t tile, 4 waves each own 16 oc.
// ---------------------------------------------------------------------------
__global__ __launch_bounds__(256) void final_kernel(
    const bf16_t* __restrict__ skip, const bf16_t* __restrict__ skpk,
    const float* __restrict__ sk_b,
    const float* __restrict__ out_W, const float* __restrict__ out_b,
    float* __restrict__ out)
{
    __shared__ uint4 tile_u[512];                       // 8KB tile
    __shared__ float part[16][66];
    unsigned char* sm = (unsigned char*)tile_u;
    int tid = threadIdx.x;
    int w = __builtin_amdgcn_readfirstlane(tid >> 6);
    int l = tid & 63, lr = l & 15, g = l >> 4;
    int b = blockIdx.y, t0 = blockIdx.x * 64;
    const bf16_t* sb = skip + (size_t)b * T * 64;

    #pragma unroll
    for (int it = 0; it < 2; ++it) {
        int q = it * 256 + tid;             // 0..511
        int row = q >> 3, c16 = q & 7;
        uint4 val = *(const uint4*)(sb + (size_t)(t0 + row) * 64 + c16 * 8);
        *(uint4*)(sm + swz(row * 128 + c16 * 16)) = val;
    }

    bf16x8 aS[2];
    #pragma unroll
    for (int kf = 0; kf < 2; ++kf)
        aS[kf] = *(const bf16x8*)(skpk + (w * 16 + lr) * 64 + kf * 32 + g * 8);
    f32x4 acc[4];
    #pragma unroll
    for (int nf = 0; nf < 4; ++nf)
        #pragma unroll
        for (int r = 0; r < 4; ++r) acc[nf][r] = sk_b[w * 16 + g * 4 + r];
    __syncthreads();

    #pragma unroll
    for (int kf = 0; kf < 2; ++kf) {
        bf16x8 Bf[4];
        #pragma unroll
        for (int nf = 0; nf < 4; ++nf) {
            int off = (nf * 16 + lr) * 128 + (kf * 32 + g * 8) * 2;
            Bf[nf] = *(const bf16x8*)(sm + swz(off));
        }
        #pragma unroll
        for (int nf = 0; nf < 4; ++nf)
            acc[nf] = __builtin_amdgcn_mfma_f32_16x16x32_bf16(aS[kf], Bf[nf], acc[nf], 0, 0, 0);
    }

    // relu + dot with out_W over this lane's 4 rows, for each of 4 t-frags
    #pragma unroll
    for (int nf = 0; nf < 4; ++nf) {
        float o = 0.f;
        #pragma unroll
        for (int r = 0; r < 4; ++r)
            o = fmaf(out_W[w * 16 + g * 4 + r], fmaxf(acc[nf][r], 0.f), o);
        part[w * 4 + g][nf * 16 + lr] = o;
    }
    __syncthreads();
    if (tid < 64) {
        float o = out_b[0];
        #pragma unroll
        for (int j = 0; j < 16; ++j) o += part[j][tid];
        out[(size_t)b * T + t0 + tid] = o;
    }
}

// ---------------------------------------------------------------------------
extern "C" void kernel_launch(void* const* d_in, const int* in_sizes, int n_in,
                              void* d_out, int out_size, void* d_ws, size_t ws_size,
                              hipStream_t stream) {
    const float* audio = (const float*)d_in[0];
    const int*   dstep = (const int*)d_in[1];
    const float* in_W  = (const float*)d_in[2];
    const float* in_b  = (const float*)d_in[3];
    const float* p1_W  = (const float*)d_in[4];
    const float* p1_b  = (const float*)d_in[5];
    const float* p2_W  = (const float*)d_in[6];
    const float* p2_b  = (const float*)d_in[7];
    const float* dw_W  = (const float*)d_in[8];
    const float* dw_b  = (const float*)d_in[9];
    const float* dp_W  = (const float*)d_in[10];
    const float* dp_b  = (const float*)d_in[11];
    const float* op_W  = (const float*)d_in[12];
    const float* op_b  = (const float*)d_in[13];
    const float* sk_W  = (const float*)d_in[14];
    const float* sk_b  = (const float*)d_in[15];
    const float* out_W = (const float*)d_in[16];
    const float* out_b = (const float*)d_in[17];

    float* ws = (float*)d_ws;
    const size_t NXE = (size_t)B * T * 64;            // elems per activation buf
    float* cond  = ws;                                 // NL*B*64
    float* h2    = cond + NL * B * C;                  // 2048
    float* bias2 = h2 + B * 512;                       // NL*B*128
    bf16_t* xA   = (bf16_t*)(bias2 + NL * B * 128);
    bf16_t* xB   = xA + NXE;
    bf16_t* skip = xB + NXE;
    bf16_t* convpk = skip + NXE;                       // NL*128*192
    bf16_t* oppk   = convpk + (size_t)NL * 128 * 192;  // NL*128*64
    bf16_t* skpk   = oppk + (size_t)NL * 128 * 64;     // 4096

    hipLaunchKernelGGL(pack_weights, dim3(3856), dim3(256), 0, stream,
                       dw_W, op_W, sk_W, convpk, oppk, skpk);
    hipLaunchKernelGGL(cond_stage1, dim3(B), dim3(512), 0, stream,
                       dstep, p1_W, p1_b, p2_W, p2_b, h2);
    hipLaunchKernelGGL(cond_stage2, dim3(NL, B), dim3(256), 0, stream,
                       h2, dp_W, dp_b, cond);
    hipLaunchKernelGGL(cond_fold, dim3(NL, B), dim3(128), 0, stream,
                       convpk, dw_b, cond, bias2);
    hipLaunchKernelGGL(in_conv, dim3(B * T * 8 / 256), dim3(256), 0, stream,
                       audio, in_W, in_b, xA);
    for (int i = 0; i < NL; ++i) {
        bf16_t* xin  = (i & 1) ? xB : xA;
        bf16_t* xout = (i & 1) ? xA : xB;
        int dil = 1 << (i % 10);
        hipLaunchKernelGGL(layer_kernel, dim3(T / 64, B), dim3(256), 0, stream,
                           xin, xout, skip, convpk, oppk, bias2, op_b, i, dil,
                           (i == 0) ? 1 : 0);
    }
    hipLaunchKernelGGL(final_kernel, dim3(T / 64, B), dim3(256), 0, stream,
                       skip, skpk, sk_b, out_W, out_b, (float*)d_out);
}

// Round 5
// 491.280 us; speedup vs baseline: 10.5884x; 1.3715x over previous
//
#include <hip/hip_runtime.h>
#include <math.h>

#define C 64
#define NL 30
#define T 16384
#define B 4

typedef __bf16 bf16_t;
typedef __bf16 bf16x8 __attribute__((ext_vector_type(8)));
typedef __bf16 bf16x4 __attribute__((ext_vector_type(4)));
typedef float f32x4 __attribute__((ext_vector_type(4)));

typedef const __attribute__((address_space(1))) unsigned int glb_u32;
typedef __attribute__((address_space(3))) unsigned int lds_u32;

constexpr float INV_SQRT2   = 0.70710678118654752440f;
constexpr float INV_SQRT_NL = 0.18257418583505537115f; // 1/sqrt(30)

__device__ __forceinline__ float fsig(float x) {
    return __builtin_amdgcn_rcpf(1.f + __builtin_amdgcn_exp2f(-1.44269504089f * x));
}
__device__ __forceinline__ float ftanh(float x) {
    return fmaf(2.f, __builtin_amdgcn_rcpf(1.f + __builtin_amdgcn_exp2f(-2.88539008178f * x)), -1.f);
}
// XOR swizzle for 128-byte-row LDS tiles (G4): byte ^= ((row&7)<<4)
__device__ __forceinline__ int swz(int off) { return off ^ ((off >> 3) & 0x70); }

// ---------------------------------------------------------------------------
// Pack weights to bf16 K-contiguous rows:
//   convpk[l][oc][k], k = tap*64+ic ; oppk[l][oc][ic] ; skpk[oc][ic]*1/sqrt(30)
// ---------------------------------------------------------------------------
__global__ void pack_weights(const float* __restrict__ dw_W,
                             const float* __restrict__ op_W,
                             const float* __restrict__ sk_W,
                             bf16_t* __restrict__ convpk,
                             bf16_t* __restrict__ oppk,
                             bf16_t* __restrict__ skpk) {
    int idx = blockIdx.x * 256 + threadIdx.x;
    const int ndw = NL * 128 * 192;
    const int nop = NL * 128 * 64;
    if (idx < ndw) {
        int k = idx % 192; int r = idx / 192;
        int oc = r % 128;  int l = r / 128;
        int tap = k >> 6, ic = k & 63;
        convpk[idx] = (bf16_t)dw_W[((l * 128 + oc) * 64 + ic) * 3 + tap];
    } else if (idx < ndw + nop) {
        oppk[idx - ndw] = (bf16_t)op_W[idx - ndw];
    } else if (idx < ndw + nop + 4096) {
        int j = idx - ndw - nop;
        skpk[j] = (bf16_t)(sk_W[j] * INV_SQRT_NL);
    }
}

// ---------------------------------------------------------------------------
// Cond: emb -> p1 (silu). grid (B, 8): block owns 64 outputs, 4-way split-K.
// ---------------------------------------------------------------------------
__global__ void cond_embp1(const int* __restrict__ step,
                           const float* __restrict__ p1_W, const float* __restrict__ p1_b,
                           float* __restrict__ h1out) {
    __shared__ float e[128];
    __shared__ float red[256];
    int b = blockIdx.x, blk = blockIdx.y, tid = threadIdx.x;
    int s = step[b];
    if (tid < 128) {
        int d = tid & 63;
        float tf = (float)s * powf(10.f, (float)d * 4.f / 63.f);
        double td = (double)tf;
        e[tid] = (tid < 64) ? (float)sin(td) : (float)cos(td);
    }
    __syncthreads();
    int ol = tid >> 2, q = tid & 3;
    int o = blk * 64 + ol;
    const float4* wr = (const float4*)(p1_W + o * 128 + q * 32);
    const float4* ev = (const float4*)(e + q * 32);
    float a = 0.f;
    #pragma unroll
    for (int j = 0; j < 8; ++j) {
        float4 wv = wr[j]; float4 xv = ev[j];
        a = fmaf(wv.x, xv.x, a); a = fmaf(wv.y, xv.y, a);
        a = fmaf(wv.z, xv.z, a); a = fmaf(wv.w, xv.w, a);
    }
    red[tid] = a;
    __syncthreads();
    if (q == 0) {
        float v = red[tid] + red[tid + 1] + red[tid + 2] + red[tid + 3] + p1_b[o];
        h1out[b * 512 + o] = v / (1.f + expf(-v));
    }
}

// ---------------------------------------------------------------------------
// Cond: p2 (silu). grid (B, 8): block owns 64 outputs, 4-way split-K (K=512).
// ---------------------------------------------------------------------------
__global__ void cond_p2(const float* __restrict__ h1,
                        const float* __restrict__ p2_W, const float* __restrict__ p2_b,
                        float* __restrict__ h2out) {
    __shared__ float red[256];
    int b = blockIdx.x, blk = blockIdx.y, tid = threadIdx.x;
    int ol = tid >> 2, q = tid & 3;
    int o = blk * 64 + ol;
    const float4* wr = (const float4*)(p2_W + o * 512 + q * 128);
    const float4* hv = (const float4*)(h1 + b * 512 + q * 128);
    float a = 0.f;
    #pragma unroll 8
    for (int j = 0; j < 32; ++j) {
        float4 wv = wr[j]; float4 xv = hv[j];
        a = fmaf(wv.x, xv.x, a); a = fmaf(wv.y, xv.y, a);
        a = fmaf(wv.z, xv.z, a); a = fmaf(wv.w, xv.w, a);
    }
    red[tid] = a;
    __syncthreads();
    if (q == 0) {
        float v = red[tid] + red[tid + 1] + red[tid + 2] + red[tid + 3] + p2_b[o];
        h2out[b * 512 + o] = v / (1.f + expf(-v));
    }
}

// ---------------------------------------------------------------------------
// Cond stage 2: cond[l][b][c] = dp_W[l] @ h2[b] + dp_b[l]
// ---------------------------------------------------------------------------
__global__ void cond_stage2(const float* __restrict__ h2,
                            const float* __restrict__ dp_W, const float* __restrict__ dp_b,
                            float* __restrict__ cond) {
    __shared__ float part[256];
    int l = blockIdx.x, b = blockIdx.y;
    int tid = threadIdx.x;
    int o = tid >> 2, q = tid & 3;
    const float4* wr = (const float4*)(dp_W + ((size_t)l * C + o) * 512 + q * 128);
    const float4* h = (const float4*)(h2 + b * 512 + q * 128);
    float a = 0.f;
    #pragma unroll 8
    for (int j = 0; j < 32; ++j) {
        float4 wv = wr[j]; float4 hv = h[j];
        a = fmaf(wv.x, hv.x, a); a = fmaf(wv.y, hv.y, a);
        a = fmaf(wv.z, hv.z, a); a = fmaf(wv.w, hv.w, a);
    }
    part[tid] = a;
    __syncthreads();
    if (q == 0) {
        cond[(l * B + b) * C + o] =
            part[tid] + part[tid + 1] + part[tid + 2] + part[tid + 3] + dp_b[l * C + o];
    }
}

// ---------------------------------------------------------------------------
// Fold cond into conv bias: bias2[l][b][oc] = dw_b[l][oc] + sum_k W[oc][k]*cond[k&63]
// ---------------------------------------------------------------------------
__global__ void cond_fold(const bf16_t* __restrict__ convpk,
                          const float* __restrict__ dw_b,
                          const float* __restrict__ cond,
                          float* __restrict__ bias2) {
    int l = blockIdx.x, b = blockIdx.y;
    int oc = threadIdx.x;                      // 128 threads
    const bf16_t* wr = convpk + ((size_t)l * 128 + oc) * 192;
    const float* cd = cond + (l * B + b) * C;
    float a = dw_b[l * 128 + oc];
    #pragma unroll 3
    for (int tap = 0; tap < 3; ++tap) {
        #pragma unroll
        for (int ic = 0; ic < 64; ++ic)
            a = fmaf((float)wr[tap * 64 + ic], cd[ic], a);
    }
    bias2[(l * B + b) * 128 + oc] = a;
}

// ---------------------------------------------------------------------------
// Input 1x1 conv + ReLU -> x[b][t][c] bf16. Thread handles 8 channels.
// ---------------------------------------------------------------------------
__global__ void in_conv(const float* __restrict__ audio,
                        const float* __restrict__ in_W, const float* __restrict__ in_b,
                        bf16_t* __restrict__ x) {
    int idx = blockIdx.x * 256 + threadIdx.x;   // over B*T*8
    int cb = idx & 7;
    int t = (idx >> 3) & (T - 1);
    int b = idx >> 17;
    float av = audio[b * T + t];
    bf16x8 o;
    #pragma unroll
    for (int j = 0; j < 8; ++j) {
        int c = cb * 8 + j;
        o[j] = (bf16_t)fmaxf(fmaf(in_W[c], av, in_b[c]), 0.f);
    }
    *(bf16x8*)(x + ((size_t)b * T + t) * 64 + cb * 8) = o;
}

// ---------------------------------------------------------------------------
// One residual layer. x layout [b][t][c] bf16. 256 thr = 4 waves.
// Block processes 128 t as TWO 64-t sub-tiles (amortizes weight regs/fetch).
// Staging: global_load_lds width=16, swizzle applied on the GLOBAL source
// (c16 ^= row&7) with linear LDS dest; OOB taps read a zeroed page.
// Wave w owns conv rows {w*16..+16} (gate) and {64+w*16..+16} (filt): the
// gate/filt pair sits in the same lane/reg -> gating needs no exchange.
// LDS: 3 tap slices [64t][64c] bf16 (24KB) + z tile (8KB), XOR-swizzled.
// ---------------------------------------------------------------------------
__global__ __launch_bounds__(256) void layer_kernel(
    const bf16_t* __restrict__ x_in, bf16_t* __restrict__ x_out, bf16_t* __restrict__ skip,
    const bf16_t* __restrict__ convpk, const bf16_t* __restrict__ oppk,
    const float* __restrict__ bias2, const float* __restrict__ op_b,
    const bf16_t* __restrict__ zpage,
    int layer, int dil, int first)
{
    __shared__ uint4 smem_u[2048];                       // 32768 B
    char* sm = (char*)smem_u;

    int tid = threadIdx.x;
    int w = __builtin_amdgcn_readfirstlane(tid >> 6);
    int l = tid & 63;
    int lr = l & 15;
    int g = l >> 4;
    int b = blockIdx.y;
    int tbase = blockIdx.x * 128;
    const bf16_t* xb = x_in + (size_t)b * T * 64;

    // ---- A fragments (weights) in registers, loaded once per block -------
    bf16x8 cA[2][6];
    const bf16_t* cw = convpk + (size_t)layer * 128 * 192;
    #pragma unroll
    for (int mf = 0; mf < 2; ++mf)
        #pragma unroll
        for (int kf = 0; kf < 6; ++kf)
            cA[mf][kf] = *(const bf16x8*)(cw + (mf * 64 + w * 16 + lr) * 192 + kf * 32 + g * 8);
    bf16x8 oA[2][2];
    const bf16_t* ow = oppk + (size_t)layer * 128 * 64;
    #pragma unroll
    for (int mf = 0; mf < 2; ++mf)
        #pragma unroll
        for (int kf = 0; kf < 2; ++kf)
            oA[mf][kf] = *(const bf16x8*)(ow + (mf * 64 + w * 16 + lr) * 64 + kf * 32 + g * 8);

    // ---- biases (cond folded into conv bias) -----------------------------
    f32x4 bC[2], bO[2];
    const float* b2 = bias2 + (layer * B + b) * 128;
    const float* ob = op_b + layer * 2 * C;
    #pragma unroll
    for (int mf = 0; mf < 2; ++mf)
        #pragma unroll
        for (int r = 0; r < 4; ++r) {
            bC[mf][r] = b2[mf * 64 + w * 16 + g * 4 + r];
            bO[mf][r] = ob[mf * 64 + w * 16 + g * 4 + r];
        }

    size_t bb = (size_t)b * T * 64;

    for (int st = 0; st < 2; ++st) {
        int t0 = tbase + st * 64;

        // ---- stage: 6 x global_load_lds(16B) per thread ------------------
        #pragma unroll
        for (int it = 0; it < 6; ++it) {
            int qq = it * 256 + w * 64 + l;
            int slice = qq >> 9;
            int row = (qq >> 3) & 63;
            int c16 = qq & 7;
            int ts = t0 + row + (slice - 1) * dil;
            int c16s = c16 ^ (row & 7);            // swizzle on SOURCE
            const bf16_t* src = ((unsigned)ts < (unsigned)T)
                ? (xb + (size_t)ts * 64 + c16s * 8)
                : (zpage + c16s * 8);
            __builtin_amdgcn_global_load_lds(
                (glb_u32*)src,
                (lds_u32*)(sm + (it * 256 + w * 64) * 16),   // wave-uniform base
                16, 0, 0);
        }
        __syncthreads();

        // ---- conv GEMM: K = 3 taps x 64 c --------------------------------
        f32x4 acc[2][4];
        #pragma unroll
        for (int mf = 0; mf < 2; ++mf)
            #pragma unroll
            for (int nf = 0; nf < 4; ++nf) acc[mf][nf] = bC[mf];
        #pragma unroll
        for (int kf = 0; kf < 6; ++kf) {
            int tap = kf >> 1;
            int kc = (kf & 1) * 32;
            bf16x8 Bf[4];
            #pragma unroll
            for (int nf = 0; nf < 4; ++nf) {
                int off = tap * 8192 + (nf * 16 + lr) * 128 + (kc + g * 8) * 2;
                Bf[nf] = *(const bf16x8*)(sm + swz(off));
            }
            #pragma unroll
            for (int mf = 0; mf < 2; ++mf)
                #pragma unroll
                for (int nf = 0; nf < 4; ++nf)
                    acc[mf][nf] = __builtin_amdgcn_mfma_f32_16x16x32_bf16(
                        cA[mf][kf], Bf[nf], acc[mf][nf], 0, 0, 0);
        }

        // ---- gating in-lane, z -> LDS in B-frag layout -------------------
        #pragma unroll
        for (int nf = 0; nf < 4; ++nf) {
            union { bf16_t h[4]; uint2 u; } zp;
            #pragma unroll
            for (int r = 0; r < 4; ++r)
                zp.h[r] = (bf16_t)(fsig(acc[0][nf][r]) * ftanh(acc[1][nf][r]));
            int off = 24576 + (nf * 16 + lr) * 128 + (w * 16 + g * 4) * 2;
            *(uint2*)(sm + swz(off)) = zp.u;
        }
        __syncthreads();

        // ---- op 1x1 GEMM --------------------------------------------------
        f32x4 acc2[2][4];
        #pragma unroll
        for (int mf = 0; mf < 2; ++mf)
            #pragma unroll
            for (int nf = 0; nf < 4; ++nf) acc2[mf][nf] = bO[mf];
        #pragma unroll
        for (int kf = 0; kf < 2; ++kf) {
            bf16x8 Zf[4];
            #pragma unroll
            for (int nf = 0; nf < 4; ++nf) {
                int off = 24576 + (nf * 16 + lr) * 128 + (kf * 32 + g * 8) * 2;
                Zf[nf] = *(const bf16x8*)(sm + swz(off));
            }
            #pragma unroll
            for (int mf = 0; mf < 2; ++mf)
                #pragma unroll
                for (int nf = 0; nf < 4; ++nf)
                    acc2[mf][nf] = __builtin_amdgcn_mfma_f32_16x16x32_bf16(
                        oA[mf][kf], Zf[nf], acc2[mf][nf], 0, 0, 0);
        }

        // ---- epilogue: residual + skip, [t][c] bf16 ----------------------
        #pragma unroll
        for (int nf = 0; nf < 4; ++nf) {
            int t = t0 + nf * 16 + lr;
            int c0 = w * 16 + g * 4;
            int xoff = 8192 + (nf * 16 + lr) * 128 + c0 * 2;   // tap-1 slice
            bf16x4 xv = *(const bf16x4*)(sm + swz(xoff));
            bf16x4 ro, so;
            bf16_t* sp = skip + bb + (size_t)t * 64 + c0;
            if (first) {
                #pragma unroll
                for (int r = 0; r < 4; ++r) {
                    ro[r] = (bf16_t)(((float)xv[r] + acc2[0][nf][r]) * INV_SQRT2);
                    so[r] = (bf16_t)acc2[1][nf][r];
                }
            } else {
                bf16x4 sv = *(const bf16x4*)sp;
                #pragma unroll
                for (int r = 0; r < 4; ++r) {
                    ro[r] = (bf16_t)(((float)xv[r] + acc2[0][nf][r]) * INV_SQRT2);
                    so[r] = (bf16_t)((float)sv[r] + acc2[1][nf][r]);
                }
            }
            *(bf16x4*)(x_out + bb + (size_t)t * 64 + c0) = ro;
            *(bf16x4*)sp = so;
        }
        if (st == 0) __syncthreads();   // LDS reuse fence
    }
}

// ---------------------------------------------------------------------------
// Final: skip(bf16,[t][c]) -> sk conv (MFMA, weights pre-scaled by 1/sqrt30)
// -> relu -> dot with out_W + out_b. Block = 64-t tile, 4 waves each own 16 oc.
// ---------------------------------------------------------------------------
__global__ __launch_bounds__(256) void final_kernel(
    const bf16_t* __restrict__ skip, const bf16_t* __restrict__ skpk,
    const float* __restrict__ sk_b,
    const float* __restrict__ out_W, const float* __restrict__ out_b,
    float* __restrict__ out)
{
    __shared__ uint4 tile_u[512];                       // 8KB tile
    __shared__ float part[16][66];
    unsigned char* sm = (unsigned char*)tile_u;
    int tid = threadIdx.x;
    int w = __builtin_amdgcn_readfirstlane(tid >> 6);
    int l = tid & 63, lr = l & 15, g = l >> 4;
    int b = blockIdx.y, t0 = blockIdx.x * 64;
    const bf16_t* sb = skip + (size_t)b * T * 64;

    #pragma unroll
    for (int it = 0; it < 2; ++it) {
        int q = it * 256 + tid;             // 0..511
        int row = q >> 3, c16 = q & 7;
        uint4 val = *(const uint4*)(sb + (size_t)(t0 + row) * 64 + c16 * 8);
        *(uint4*)(sm + swz(row * 128 + c16 * 16)) = val;
    }

    bf16x8 aS[2];
    #pragma unroll
    for (int kf = 0; kf < 2; ++kf)
        aS[kf] = *(const bf16x8*)(skpk + (w * 16 + lr) * 64 + kf * 32 + g * 8);
    f32x4 acc[4];
    #pragma unroll
    for (int nf = 0; nf < 4; ++nf)
        #pragma unroll
        for (int r = 0; r < 4; ++r) acc[nf][r] = sk_b[w * 16 + g * 4 + r];
    __syncthreads();

    #pragma unroll
    for (int kf = 0; kf < 2; ++kf) {
        bf16x8 Bf[4];
        #pragma unroll
        for (int nf = 0; nf < 4; ++nf) {
            int off = (nf * 16 + lr) * 128 + (kf * 32 + g * 8) * 2;
            Bf[nf] = *(const bf16x8*)(sm + swz(off));
        }
        #pragma unroll
        for (int nf = 0; nf < 4; ++nf)
            acc[nf] = __builtin_amdgcn_mfma_f32_16x16x32_bf16(aS[kf], Bf[nf], acc[nf], 0, 0, 0);
    }

    #pragma unroll
    for (int nf = 0; nf < 4; ++nf) {
        float o = 0.f;
        #pragma unroll
        for (int r = 0; r < 4; ++r)
            o = fmaf(out_W[w * 16 + g * 4 + r], fmaxf(acc[nf][r], 0.f), o);
        part[w * 4 + g][nf * 16 + lr] = o;
    }
    __syncthreads();
    if (tid < 64) {
        float o = out_b[0];
        #pragma unroll
        for (int j = 0; j < 16; ++j) o += part[j][tid];
        out[(size_t)b * T + t0 + tid] = o;
    }
}

// ---------------------------------------------------------------------------
extern "C" void kernel_launch(void* const* d_in, const int* in_sizes, int n_in,
                              void* d_out, int out_size, void* d_ws, size_t ws_size,
                              hipStream_t stream) {
    const float* audio = (const float*)d_in[0];
    const int*   dstep = (const int*)d_in[1];
    const float* in_W  = (const float*)d_in[2];
    const float* in_b  = (const float*)d_in[3];
    const float* p1_W  = (const float*)d_in[4];
    const float* p1_b  = (const float*)d_in[5];
    const float* p2_W  = (const float*)d_in[6];
    const float* p2_b  = (const float*)d_in[7];
    const float* dw_W  = (const float*)d_in[8];
    const float* dw_b  = (const float*)d_in[9];
    const float* dp_W  = (const float*)d_in[10];
    const float* dp_b  = (const float*)d_in[11];
    const float* op_W  = (const float*)d_in[12];
    const float* op_b  = (const float*)d_in[13];
    const float* sk_W  = (const float*)d_in[14];
    const float* sk_b  = (const float*)d_in[15];
    const float* out_W = (const float*)d_in[16];
    const float* out_b = (const float*)d_in[17];

    float* ws = (float*)d_ws;
    const size_t NXE = (size_t)B * T * 64;             // elems per activation buf
    float* cond  = ws;                                  // NL*B*64
    float* h1    = cond + NL * B * C;                   // B*512
    float* h2    = h1 + B * 512;                        // B*512
    float* bias2 = h2 + B * 512;                        // NL*B*128
    float* zpg   = bias2 + NL * B * 128;                // 128 floats (512B zero page)
    bf16_t* xA   = (bf16_t*)(zpg + 128);
    bf16_t* xB   = xA + NXE;
    bf16_t* skip = xB + NXE;
    bf16_t* convpk = skip + NXE;                        // NL*128*192
    bf16_t* oppk   = convpk + (size_t)NL * 128 * 192;   // NL*128*64
    bf16_t* skpk   = oppk + (size_t)NL * 128 * 64;      // 4096

    hipMemsetAsync(zpg, 0, 512, stream);
    hipLaunchKernelGGL(pack_weights, dim3(3856), dim3(256), 0, stream,
                       dw_W, op_W, sk_W, convpk, oppk, skpk);
    hipLaunchKernelGGL(cond_embp1, dim3(B, 8), dim3(256), 0, stream,
                       dstep, p1_W, p1_b, h1);
    hipLaunchKernelGGL(cond_p2, dim3(B, 8), dim3(256), 0, stream,
                       h1, p2_W, p2_b, h2);
    hipLaunchKernelGGL(cond_stage2, dim3(NL, B), dim3(256), 0, stream,
                       h2, dp_W, dp_b, cond);
    hipLaunchKernelGGL(cond_fold, dim3(NL, B), dim3(128), 0, stream,
                       convpk, dw_b, cond, bias2);
    hipLaunchKernelGGL(in_conv, dim3(B * T * 8 / 256), dim3(256), 0, stream,
                       audio, in_W, in_b, xA);
    for (int i = 0; i < NL; ++i) {
        bf16_t* xin  = (i & 1) ? xB : xA;
        bf16_t* xout = (i & 1) ? xA : xB;
        int dil = 1 << (i % 10);
        hipLaunchKernelGGL(layer_kernel, dim3(T / 128, B), dim3(256), 0, stream,
                           xin, xout, skip, convpk, oppk, bias2, op_b,
                           (const bf16_t*)zpg, i, dil, (i == 0) ? 1 : 0);
    }
    hipLaunchKernelGGL(final_kernel, dim3(T / 64, B), dim3(256), 0, stream,
                       skip, skpk, sk_b, out_W, out_b, (float*)d_out);
}